// Round 1
// baseline (1164.884 us; speedup 1.0000x reference)
//
#include <hip/hip_runtime.h>

#define N_CLASS 100
#define D 256
#define DECAYF 0.3f
#define KEEPF 0.7f
#define THRESH 0.9f

// ---------------------------------------------------------------------------
// Kernel A: per-row argmax (first-index tie-break) + max over 100 class scores.
// One wave (64 lanes) per row. gridDim.y selects tensor (0=s, 1=t).
// ---------------------------------------------------------------------------
__global__ void argmax_kernel(const float* __restrict__ yS, const float* __restrict__ yT,
                              int* __restrict__ lblS, int* __restrict__ lblT,
                              float* __restrict__ wS, float* __restrict__ wT,
                              int* __restrict__ counts, int n) {
    const int tensor = blockIdx.y;
    const float* __restrict__ y = tensor ? yT : yS;
    int* __restrict__ lbl = tensor ? lblT : lblS;
    float* __restrict__ w = tensor ? wT : wS;
    int* __restrict__ cnt = counts + tensor * N_CLASS;

    const int lane = threadIdx.x & 63;
    const int row = blockIdx.x * (blockDim.x >> 6) + (threadIdx.x >> 6);
    if (row >= n) return;

    const float* __restrict__ r = y + (size_t)row * N_CLASS;
    float v = r[lane];
    int idx = lane;
    if (lane < N_CLASS - 64) {               // lanes 0..35 cover indices 64..99
        float v2 = r[64 + lane];
        if (v2 > v) { v = v2; idx = 64 + lane; }   // strictly greater: keep lower idx on tie
    }
    // butterfly max+argmax, prefer lower index on ties (jnp.argmax semantics)
    #pragma unroll
    for (int off = 32; off; off >>= 1) {
        float ov = __shfl_xor(v, off, 64);
        int   oi = __shfl_xor(idx, off, 64);
        if (ov > v || (ov == v && oi < idx)) { v = ov; idx = oi; }
    }
    if (lane == 0) {
        lbl[row] = idx;
        w[row] = (v > THRESH) ? v : 0.0f;
        atomicAdd(cnt + idx, 1);
    }
}

// ---------------------------------------------------------------------------
// Kernel B: weighted scatter-add of features by label.
// block = (row-chunk, 64-col group, tensor). LDS acc[100][64] = 25.6 KB.
// Within a wave all 64 lanes share one row -> same label, distinct banks.
// ---------------------------------------------------------------------------
__global__ void scatter_kernel(const float* __restrict__ fS, const float* __restrict__ fT,
                               const int* __restrict__ lblS, const int* __restrict__ lblT,
                               const float* __restrict__ wS, const float* __restrict__ wT,
                               float* __restrict__ sums, int rowsPerBlock) {
    const int tensor = blockIdx.z;
    const float* __restrict__ f = tensor ? fT : fS;
    const int* __restrict__ lbl = tensor ? lblT : lblS;
    const float* __restrict__ w = tensor ? wT : wS;

    __shared__ float acc[N_CLASS * 64];
    const int tid = threadIdx.x;
    for (int i = tid; i < N_CLASS * 64; i += 256) acc[i] = 0.0f;
    __syncthreads();

    const int lane = tid & 63;
    const int wv = tid >> 6;
    const int col = blockIdx.y * 64 + lane;
    const int row0 = blockIdx.x * rowsPerBlock;

    // 4x row unroll; rowsPerBlock is a multiple of 16, 4 waves stride rows mod 4
    for (int r = row0 + wv; r < row0 + rowsPerBlock; r += 16) {
        const int r0 = r, r1 = r + 4, r2 = r + 8, r3 = r + 12;
        float v0 = f[(size_t)r0 * D + col];
        float v1 = f[(size_t)r1 * D + col];
        float v2 = f[(size_t)r2 * D + col];
        float v3 = f[(size_t)r3 * D + col];
        int l0 = lbl[r0], l1 = lbl[r1], l2 = lbl[r2], l3 = lbl[r3];
        float w0 = w[r0], w1 = w[r1], w2 = w[r2], w3 = w[r3];
        atomicAdd(&acc[l0 * 64 + lane], w0 * v0);
        atomicAdd(&acc[l1 * 64 + lane], w1 * v1);
        atomicAdd(&acc[l2 * 64 + lane], w2 * v2);
        atomicAdd(&acc[l3 * 64 + lane], w3 * v3);
    }
    __syncthreads();

    float* __restrict__ gs = sums + (size_t)tensor * N_CLASS * D + blockIdx.y * 64;
    for (int i = tid; i < N_CLASS * 64; i += 256) {
        int c = i >> 6;
        int l = i & 63;
        unsafeAtomicAdd(&gs[c * D + l], acc[i]);
    }
}

// ---------------------------------------------------------------------------
// Kernel C: centroid EMA + MSE reduction. 100 blocks x 256 threads.
// ---------------------------------------------------------------------------
__global__ void finalize_kernel(const float* __restrict__ sums, const int* __restrict__ counts,
                                const float* __restrict__ cS, const float* __restrict__ cT,
                                float* __restrict__ out) {
    const int c = blockIdx.x;
    const int j = threadIdx.x;   // column 0..255

    float cntS = fmaxf((float)counts[c], 1.0f);
    float cntT = fmaxf((float)counts[N_CLASS + c], 1.0f);

    float sc = KEEPF * cS[c * D + j] + DECAYF * sums[c * D + j] / cntS;
    float tc = KEEPF * cT[c * D + j] + DECAYF * sums[(size_t)N_CLASS * D + c * D + j] / cntT;
    float d = sc - tc;
    float val = d * d;

    #pragma unroll
    for (int off = 32; off; off >>= 1) val += __shfl_xor(val, off, 64);

    __shared__ float red[4];
    if ((j & 63) == 0) red[j >> 6] = val;
    __syncthreads();
    if (j == 0) {
        float t = (red[0] + red[1] + red[2] + red[3]) * (1.0f / (N_CLASS * D));
        unsafeAtomicAdd(out, t);
    }
}

extern "C" void kernel_launch(void* const* d_in, const int* in_sizes, int n_in,
                              void* d_out, int out_size, void* d_ws, size_t ws_size,
                              hipStream_t stream) {
    const float* s_feature = (const float*)d_in[0];
    const float* t_feature = (const float*)d_in[1];
    const float* y_s = (const float*)d_in[2];
    const float* y_t = (const float*)d_in[3];
    const float* s_centroid = (const float*)d_in[4];
    const float* t_centroid = (const float*)d_in[5];
    float* out = (float*)d_out;

    const int n = in_sizes[0] / D;   // 131072

    // workspace layout
    char* ws = (char*)d_ws;
    int* lblS = (int*)ws;                        // n ints
    int* lblT = lblS + n;                        // n ints
    float* wS = (float*)(lblT + n);              // n floats
    float* wT = wS + n;                          // n floats
    int* counts = (int*)(wT + n);                // 2*N_CLASS ints, padded to 256
    float* sums = (float*)(counts + 256);        // 2*N_CLASS*D floats

    // zero counts+sums (contiguous) and the output scalar
    hipMemsetAsync(counts, 0, 256 * sizeof(int) + (size_t)2 * N_CLASS * D * sizeof(float), stream);
    hipMemsetAsync(out, 0, sizeof(float), stream);

    // Kernel A: 4 rows per block (4 waves), y-dim = tensor
    {
        dim3 grid(n / 4, 2, 1);
        argmax_kernel<<<grid, 256, 0, stream>>>(y_s, y_t, lblS, lblT, wS, wT, counts, n);
    }
    // Kernel B: 128 row-chunks x 4 column-groups x 2 tensors
    {
        const int CHUNKS = 128;
        const int rowsPerBlock = n / CHUNKS;     // 1024, multiple of 16
        dim3 grid(CHUNKS, 4, 2);
        scatter_kernel<<<grid, 256, 0, stream>>>(s_feature, t_feature, lblS, lblT, wS, wT,
                                                 sums, rowsPerBlock);
    }
    // Kernel C
    finalize_kernel<<<100, 256, 0, stream>>>(sums, counts, s_centroid, t_centroid, out);
}

// Round 2
// 633.589 us; speedup vs baseline: 1.8385x; 1.8385x over previous
//
#include <hip/hip_runtime.h>

#define N_CLASS 100
#define D 256
#define DECAYF 0.3f
#define KEEPF 0.7f
#define THRESH 0.9f
#define NBLK_A 1024   // blocks per tensor for argmax kernel

// ---------------------------------------------------------------------------
// Kernel A: per-row argmax (first-index tie-break) + max over 100 scores.
// One wave per row-iteration; LDS count histogram; NON-ATOMIC partial flush.
// cnt_part layout: [tensor][class][NBLK_A]  (coalesced for finalize reads)
// ---------------------------------------------------------------------------
__global__ void argmax_kernel(const float* __restrict__ yS, const float* __restrict__ yT,
                              int* __restrict__ lblS, int* __restrict__ lblT,
                              float* __restrict__ wS, float* __restrict__ wT,
                              int* __restrict__ cntPart, int n) {
    const int tensor = blockIdx.y;
    const float* __restrict__ y = tensor ? yT : yS;
    int* __restrict__ lbl = tensor ? lblT : lblS;
    float* __restrict__ w = tensor ? wT : wS;

    __shared__ int hist[N_CLASS];
    for (int i = threadIdx.x; i < N_CLASS; i += 256) hist[i] = 0;
    __syncthreads();

    const int lane = threadIdx.x & 63;
    const int wv = threadIdx.x >> 6;
    const int rowsPer = n / NBLK_A;              // 128
    const int row0 = blockIdx.x * rowsPer;

    for (int r = row0 + wv; r < row0 + rowsPer; r += 4) {
        const float* __restrict__ rp = y + (size_t)r * N_CLASS;
        float v = rp[lane];
        int idx = lane;
        if (lane < N_CLASS - 64) {               // lanes 0..35 cover 64..99
            float v2 = rp[64 + lane];
            if (v2 > v) { v = v2; idx = 64 + lane; }  // strict >: lower idx wins ties
        }
        #pragma unroll
        for (int off = 32; off; off >>= 1) {
            float ov = __shfl_xor(v, off, 64);
            int   oi = __shfl_xor(idx, off, 64);
            if (ov > v || (ov == v && oi < idx)) { v = ov; idx = oi; }
        }
        if (lane == 0) {
            lbl[r] = idx;
            w[r] = (v > THRESH) ? v : 0.0f;
            atomicAdd(&hist[idx], 1);            // LDS atomic: cheap
        }
    }
    __syncthreads();
    for (int c = threadIdx.x; c < N_CLASS; c += 256)
        cntPart[(tensor * N_CLASS + c) * NBLK_A + blockIdx.x] = hist[c];
}

// ---------------------------------------------------------------------------
// Kernel B: weighted scatter-add by label into LDS acc[100][64]; NON-ATOMIC
// flush to a private slice of sums_part[tensor][chunk][colgrp][100*64].
// ---------------------------------------------------------------------------
__global__ void scatter_kernel(const float* __restrict__ fS, const float* __restrict__ fT,
                               const int* __restrict__ lblS, const int* __restrict__ lblT,
                               const float* __restrict__ wS, const float* __restrict__ wT,
                               float* __restrict__ sumsPart, int rowsPerBlock, int chunks) {
    const int tensor = blockIdx.z;
    const float* __restrict__ f = tensor ? fT : fS;
    const int* __restrict__ lbl = tensor ? lblT : lblS;
    const float* __restrict__ w = tensor ? wT : wS;

    __shared__ float acc[N_CLASS * 64];
    const int tid = threadIdx.x;
    for (int i = tid; i < N_CLASS * 64; i += 256) acc[i] = 0.0f;
    __syncthreads();

    const int lane = tid & 63;
    const int wv = tid >> 6;
    const int col = blockIdx.y * 64 + lane;
    const int row0 = blockIdx.x * rowsPerBlock;

    for (int r = row0 + wv; r < row0 + rowsPerBlock; r += 16) {
        const int r0 = r, r1 = r + 4, r2 = r + 8, r3 = r + 12;
        float v0 = f[(size_t)r0 * D + col];
        float v1 = f[(size_t)r1 * D + col];
        float v2 = f[(size_t)r2 * D + col];
        float v3 = f[(size_t)r3 * D + col];
        int l0 = lbl[r0], l1 = lbl[r1], l2 = lbl[r2], l3 = lbl[r3];
        float w0 = w[r0], w1 = w[r1], w2 = w[r2], w3 = w[r3];
        atomicAdd(&acc[l0 * 64 + lane], w0 * v0);
        atomicAdd(&acc[l1 * 64 + lane], w1 * v1);
        atomicAdd(&acc[l2 * 64 + lane], w2 * v2);
        atomicAdd(&acc[l3 * 64 + lane], w3 * v3);
    }
    __syncthreads();

    float* __restrict__ gp = sumsPart +
        (size_t)((tensor * chunks + blockIdx.x) * 4 + blockIdx.y) * (N_CLASS * 64);
    for (int i = tid; i < N_CLASS * 64; i += 256) gp[i] = acc[i];   // coalesced stores
}

// ---------------------------------------------------------------------------
// Kernel C: reduce counts + partial sums, EMA, MSE. 100 blocks x 256 threads.
// ---------------------------------------------------------------------------
__global__ void finalize_kernel(const float* __restrict__ sumsPart, const int* __restrict__ cntPart,
                                const float* __restrict__ cS, const float* __restrict__ cT,
                                float* __restrict__ out, int chunks) {
    const int c = blockIdx.x;
    const int tid = threadIdx.x;
    const int lane = tid & 63;
    const int wv = tid >> 6;

    // ---- count reduction over NBLK_A slots per tensor ----
    __shared__ float sCnt[2];
    __shared__ int redC[8];
    #pragma unroll
    for (int t = 0; t < 2; ++t) {
        int s = 0;
        for (int i = tid; i < NBLK_A; i += 256)
            s += cntPart[(t * N_CLASS + c) * NBLK_A + i];
        #pragma unroll
        for (int off = 32; off; off >>= 1) s += __shfl_xor(s, off, 64);
        if (lane == 0) redC[t * 4 + wv] = s;
    }
    __syncthreads();
    if (tid == 0) {
        sCnt[0] = fmaxf((float)(redC[0] + redC[1] + redC[2] + redC[3]), 1.0f);
        sCnt[1] = fmaxf((float)(redC[4] + redC[5] + redC[6] + redC[7]), 1.0f);
    }

    // ---- sums reduction: thread = (chunk-stripe p, col-quad q) ----
    const int p = wv;                 // chunk stripe 0..3
    const int q = lane;               // col quad 0..63 -> cols 4q..4q+3
    const int grp = q >> 4;           // 64-col group 0..3
    const int coloff = (q & 15) * 4;  // offset within group

    float4 aS = {0.f, 0.f, 0.f, 0.f}, aT = {0.f, 0.f, 0.f, 0.f};
    for (int ch = p; ch < chunks; ch += 4) {
        const float4 vS = *(const float4*)(sumsPart +
            (size_t)((0 * chunks + ch) * 4 + grp) * (N_CLASS * 64) + c * 64 + coloff);
        const float4 vT = *(const float4*)(sumsPart +
            (size_t)((1 * chunks + ch) * 4 + grp) * (N_CLASS * 64) + c * 64 + coloff);
        aS.x += vS.x; aS.y += vS.y; aS.z += vS.z; aS.w += vS.w;
        aT.x += vT.x; aT.y += vT.y; aT.z += vT.z; aT.w += vT.w;
    }
    __shared__ float4 redS[4 * 64], redT[4 * 64];
    redS[p * 64 + q] = aS;
    redT[p * 64 + q] = aT;
    __syncthreads();

    if (tid < 64) {   // wave 0: 64 lanes x 4 cols = 256 cols
        float4 sS = redS[tid], sT = redT[tid];
        #pragma unroll
        for (int pp = 1; pp < 4; ++pp) {
            float4 a = redS[pp * 64 + tid], b = redT[pp * 64 + tid];
            sS.x += a.x; sS.y += a.y; sS.z += a.z; sS.w += a.w;
            sT.x += b.x; sT.y += b.y; sT.z += b.z; sT.w += b.w;
        }
        const float invS = 1.0f / sCnt[0];
        const float invT = 1.0f / sCnt[1];
        const float4 pS = ((const float4*)cS)[c * 64 + tid];
        const float4 pT = ((const float4*)cT)[c * 64 + tid];
        float dx = (KEEPF * pS.x + DECAYF * sS.x * invS) - (KEEPF * pT.x + DECAYF * sT.x * invT);
        float dy = (KEEPF * pS.y + DECAYF * sS.y * invS) - (KEEPF * pT.y + DECAYF * sT.y * invT);
        float dz = (KEEPF * pS.z + DECAYF * sS.z * invS) - (KEEPF * pT.z + DECAYF * sT.z * invT);
        float dw = (KEEPF * pS.w + DECAYF * sS.w * invS) - (KEEPF * pT.w + DECAYF * sT.w * invT);
        float val = dx * dx + dy * dy + dz * dz + dw * dw;
        #pragma unroll
        for (int off = 32; off; off >>= 1) val += __shfl_xor(val, off, 64);
        if (tid == 0) unsafeAtomicAdd(out, val * (1.0f / (N_CLASS * D)));
    }
}

extern "C" void kernel_launch(void* const* d_in, const int* in_sizes, int n_in,
                              void* d_out, int out_size, void* d_ws, size_t ws_size,
                              hipStream_t stream) {
    const float* s_feature = (const float*)d_in[0];
    const float* t_feature = (const float*)d_in[1];
    const float* y_s = (const float*)d_in[2];
    const float* y_t = (const float*)d_in[3];
    const float* s_centroid = (const float*)d_in[4];
    const float* t_centroid = (const float*)d_in[5];
    float* out = (float*)d_out;

    const int n = in_sizes[0] / D;   // 131072

    // workspace layout (all 16B-aligned offsets)
    char* ws = (char*)d_ws;
    int* lblS = (int*)ws;                          // n ints
    int* lblT = lblS + n;                          // n ints
    float* wS = (float*)(lblT + n);                // n floats
    float* wT = wS + n;                            // n floats
    int* cntPart = (int*)(wT + n);                 // 2*N_CLASS*NBLK_A ints (800 KB)
    float* sumsPart = (float*)(cntPart + 2 * N_CLASS * NBLK_A);

    // pick the largest chunk count whose partial buffer fits ws
    const size_t base = (size_t)(4 * n) * 4 + (size_t)2 * N_CLASS * NBLK_A * 4;
    const size_t perChunk = (size_t)2 * 4 * N_CLASS * 64 * 4;   // 204800 B
    int chunks = 128;
    while (chunks > 16 && base + (size_t)chunks * perChunk > ws_size) chunks >>= 1;

    hipMemsetAsync(out, 0, sizeof(float), stream);

    // Kernel A: 1024 blocks/tensor, 128 rows/block
    {
        dim3 grid(NBLK_A, 2, 1);
        argmax_kernel<<<grid, 256, 0, stream>>>(y_s, y_t, lblS, lblT, wS, wT, cntPart, n);
    }
    // Kernel B: chunks x 4 column-groups x 2 tensors
    {
        const int rowsPerBlock = n / chunks;       // multiple of 16
        dim3 grid(chunks, 4, 2);
        scatter_kernel<<<grid, 256, 0, stream>>>(s_feature, t_feature, lblS, lblT, wS, wT,
                                                 sumsPart, rowsPerBlock, chunks);
    }
    // Kernel C
    finalize_kernel<<<100, 256, 0, stream>>>(sumsPart, cntPart, s_centroid, t_centroid, out, chunks);
}

// Round 3
// 627.651 us; speedup vs baseline: 1.8559x; 1.0095x over previous
//
#include <hip/hip_runtime.h>

#define N_CLASS 100
#define D 256
#define DECAYF 0.3f
#define KEEPF 0.7f
#define THRESH 0.9f
#define ROWS_PER_BLK_A 256
#define RU 16   // scatter: rows per iteration per wave

// ---------------------------------------------------------------------------
// Kernel A: thread-per-row argmax over 100 scores. 25 independent float4
// loads (fully unrolled -> deep MLP), in-register scan with strict-> compare
// (first-index tie-break = jnp.argmax). LDS histogram, non-atomic flush.
// cntPart layout: [tensor][class][nblk]
// ---------------------------------------------------------------------------
__global__ void argmax_kernel(const float* __restrict__ yS, const float* __restrict__ yT,
                              int* __restrict__ lblS, int* __restrict__ lblT,
                              float* __restrict__ wS, float* __restrict__ wT,
                              int* __restrict__ cntPart, int nblk) {
    const int tensor = blockIdx.y;
    const float* __restrict__ y = tensor ? yT : yS;
    int* __restrict__ lbl = tensor ? lblT : lblS;
    float* __restrict__ w = tensor ? wT : wS;

    __shared__ int hist[N_CLASS];
    for (int i = threadIdx.x; i < N_CLASS; i += 256) hist[i] = 0;
    __syncthreads();

    const int row = blockIdx.x * ROWS_PER_BLK_A + threadIdx.x;
    const float4* __restrict__ rp = (const float4*)(y + (size_t)row * N_CLASS);

    float best = -3.4e38f;
    int bi = 0;
    #pragma unroll
    for (int k = 0; k < 25; ++k) {      // 100 floats = exactly 25 float4
        float4 v = rp[k];
        if (v.x > best) { best = v.x; bi = 4 * k + 0; }
        if (v.y > best) { best = v.y; bi = 4 * k + 1; }
        if (v.z > best) { best = v.z; bi = 4 * k + 2; }
        if (v.w > best) { best = v.w; bi = 4 * k + 3; }
    }
    lbl[row] = bi;
    w[row] = (best > THRESH) ? best : 0.0f;
    atomicAdd(&hist[bi], 1);
    __syncthreads();
    for (int c = threadIdx.x; c < N_CLASS; c += 256)
        cntPart[(tensor * N_CLASS + c) * nblk + blockIdx.x] = hist[c];
}

// ---------------------------------------------------------------------------
// Kernel B: weighted scatter-add by label into LDS acc[100][64].
// Contiguous per-wave row span, 16-row unroll: 16 independent 256B feature
// loads + int4/float4 label/weight loads in flight per iteration.
// Non-atomic flush to sumsPart[tensor][chunk][colgrp][100*64].
// ---------------------------------------------------------------------------
__global__ void __launch_bounds__(256, 4)
scatter_kernel(const float* __restrict__ fS, const float* __restrict__ fT,
               const int* __restrict__ lblS, const int* __restrict__ lblT,
               const float* __restrict__ wS, const float* __restrict__ wT,
               float* __restrict__ sumsPart, int rowsPerBlock, int chunks) {
    const int tensor = blockIdx.z;
    const float* __restrict__ f = tensor ? fT : fS;
    const int* __restrict__ lbl = tensor ? lblT : lblS;
    const float* __restrict__ w = tensor ? wT : wS;

    __shared__ float acc[N_CLASS * 64];
    const int tid = threadIdx.x;
    for (int i = tid; i < N_CLASS * 64; i += 256) acc[i] = 0.0f;
    __syncthreads();

    const int lane = tid & 63;
    const int wv = tid >> 6;
    const int col = blockIdx.y * 64 + lane;
    const int rowsPerWave = rowsPerBlock >> 2;
    const int r0w = blockIdx.x * rowsPerBlock + wv * rowsPerWave;

    for (int r = r0w; r < r0w + rowsPerWave; r += RU) {
        float v[RU];
        int l[RU];
        float ww[RU];
        #pragma unroll
        for (int j = 0; j < RU; ++j)
            v[j] = f[(size_t)(r + j) * D + col];
        #pragma unroll
        for (int j = 0; j < RU; j += 4) {
            int4 li = *(const int4*)(lbl + r + j);
            l[j] = li.x; l[j + 1] = li.y; l[j + 2] = li.z; l[j + 3] = li.w;
            float4 wi = *(const float4*)(w + r + j);
            ww[j] = wi.x; ww[j + 1] = wi.y; ww[j + 2] = wi.z; ww[j + 3] = wi.w;
        }
        #pragma unroll
        for (int j = 0; j < RU; ++j)
            atomicAdd(&acc[l[j] * 64 + lane], ww[j] * v[j]);
    }
    __syncthreads();

    float* __restrict__ gp = sumsPart +
        (size_t)((tensor * chunks + blockIdx.x) * 4 + blockIdx.y) * (N_CLASS * 64);
    for (int i = tid; i < N_CLASS * 64; i += 256) gp[i] = acc[i];   // coalesced
}

// ---------------------------------------------------------------------------
// Kernel C: reduce counts + partial sums, EMA, MSE. 100 blocks x 256 threads.
// ---------------------------------------------------------------------------
__global__ void finalize_kernel(const float* __restrict__ sumsPart, const int* __restrict__ cntPart,
                                const float* __restrict__ cS, const float* __restrict__ cT,
                                float* __restrict__ out, int chunks, int nblk) {
    const int c = blockIdx.x;
    const int tid = threadIdx.x;
    const int lane = tid & 63;
    const int wv = tid >> 6;

    // ---- count reduction ----
    __shared__ float sCnt[2];
    __shared__ int redC[8];
    #pragma unroll
    for (int t = 0; t < 2; ++t) {
        int s = 0;
        for (int i = tid; i < nblk; i += 256)
            s += cntPart[(t * N_CLASS + c) * nblk + i];
        #pragma unroll
        for (int off = 32; off; off >>= 1) s += __shfl_xor(s, off, 64);
        if (lane == 0) redC[t * 4 + wv] = s;
    }
    __syncthreads();
    if (tid == 0) {
        sCnt[0] = fmaxf((float)(redC[0] + redC[1] + redC[2] + redC[3]), 1.0f);
        sCnt[1] = fmaxf((float)(redC[4] + redC[5] + redC[6] + redC[7]), 1.0f);
    }

    // ---- sums reduction: thread = (chunk-stripe p, col-quad q) ----
    const int p = wv;
    const int q = lane;
    const int grp = q >> 4;
    const int coloff = (q & 15) * 4;

    float4 aS = {0.f, 0.f, 0.f, 0.f}, aT = {0.f, 0.f, 0.f, 0.f};
    #pragma unroll 4
    for (int ch = p; ch < chunks; ch += 4) {
        const float4 vS = *(const float4*)(sumsPart +
            (size_t)((0 * chunks + ch) * 4 + grp) * (N_CLASS * 64) + c * 64 + coloff);
        const float4 vT = *(const float4*)(sumsPart +
            (size_t)((1 * chunks + ch) * 4 + grp) * (N_CLASS * 64) + c * 64 + coloff);
        aS.x += vS.x; aS.y += vS.y; aS.z += vS.z; aS.w += vS.w;
        aT.x += vT.x; aT.y += vT.y; aT.z += vT.z; aT.w += vT.w;
    }
    __shared__ float4 redS[4 * 64], redT[4 * 64];
    redS[p * 64 + q] = aS;
    redT[p * 64 + q] = aT;
    __syncthreads();

    if (tid < 64) {
        float4 sS = redS[tid], sT = redT[tid];
        #pragma unroll
        for (int pp = 1; pp < 4; ++pp) {
            float4 a = redS[pp * 64 + tid], b = redT[pp * 64 + tid];
            sS.x += a.x; sS.y += a.y; sS.z += a.z; sS.w += a.w;
            sT.x += b.x; sT.y += b.y; sT.z += b.z; sT.w += b.w;
        }
        const float invS = 1.0f / sCnt[0];
        const float invT = 1.0f / sCnt[1];
        const float4 pS = ((const float4*)cS)[c * 64 + tid];
        const float4 pT = ((const float4*)cT)[c * 64 + tid];
        float dx = (KEEPF * pS.x + DECAYF * sS.x * invS) - (KEEPF * pT.x + DECAYF * sT.x * invT);
        float dy = (KEEPF * pS.y + DECAYF * sS.y * invS) - (KEEPF * pT.y + DECAYF * sT.y * invT);
        float dz = (KEEPF * pS.z + DECAYF * sS.z * invS) - (KEEPF * pT.z + DECAYF * sT.z * invT);
        float dw = (KEEPF * pS.w + DECAYF * sS.w * invS) - (KEEPF * pT.w + DECAYF * sT.w * invT);
        float val = dx * dx + dy * dy + dz * dz + dw * dw;
        #pragma unroll
        for (int off = 32; off; off >>= 1) val += __shfl_xor(val, off, 64);
        if (tid == 0) unsafeAtomicAdd(out, val * (1.0f / (N_CLASS * D)));
    }
}

extern "C" void kernel_launch(void* const* d_in, const int* in_sizes, int n_in,
                              void* d_out, int out_size, void* d_ws, size_t ws_size,
                              hipStream_t stream) {
    const float* s_feature = (const float*)d_in[0];
    const float* t_feature = (const float*)d_in[1];
    const float* y_s = (const float*)d_in[2];
    const float* y_t = (const float*)d_in[3];
    const float* s_centroid = (const float*)d_in[4];
    const float* t_centroid = (const float*)d_in[5];
    float* out = (float*)d_out;

    const int n = in_sizes[0] / D;      // 131072
    const int nblk = n / ROWS_PER_BLK_A; // 512

    // workspace layout (16B-aligned)
    char* ws = (char*)d_ws;
    int* lblS = (int*)ws;                          // n ints
    int* lblT = lblS + n;                          // n ints
    float* wS = (float*)(lblT + n);                // n floats
    float* wT = wS + n;                            // n floats
    int* cntPart = (int*)(wT + n);                 // 2*N_CLASS*nblk ints
    float* sumsPart = (float*)(cntPart + 2 * N_CLASS * nblk);

    // pick the largest chunk count whose partial buffer fits ws
    const size_t base = (size_t)(4 * n) * 4 + (size_t)2 * N_CLASS * nblk * 4;
    const size_t perChunk = (size_t)2 * 4 * N_CLASS * 64 * 4;   // 204800 B
    int chunks = 256;
    while (chunks > 16 && base + (size_t)chunks * perChunk > ws_size) chunks >>= 1;

    hipMemsetAsync(out, 0, sizeof(float), stream);

    // Kernel A: thread-per-row, 512 blocks/tensor
    {
        dim3 grid(nblk, 2, 1);
        argmax_kernel<<<grid, 256, 0, stream>>>(y_s, y_t, lblS, lblT, wS, wT, cntPart, nblk);
    }
    // Kernel B: chunks x 4 column-groups x 2 tensors
    {
        const int rowsPerBlock = n / chunks;   // 512 at chunks=256
        dim3 grid(chunks, 4, 2);
        scatter_kernel<<<grid, 256, 0, stream>>>(s_feature, t_feature, lblS, lblT, wS, wT,
                                                 sumsPart, rowsPerBlock, chunks);
    }
    // Kernel C
    finalize_kernel<<<100, 256, 0, stream>>>(sumsPart, cntPart, s_centroid, t_centroid, out,
                                             chunks, nblk);
}

// Round 4
// 373.670 us; speedup vs baseline: 3.1174x; 1.6797x over previous
//
#include <hip/hip_runtime.h>

#define N_CLASS 100
#define D 256
#define DECAYF 0.3f
#define KEEPF 0.7f
#define THRESH 0.9f
#define RB 64          // rows per block in argmax/bucket kernels
#define NSLICE 8       // gather slices per class

// ---------------------------------------------------------------------------
// K1: argmax. Stage 64 rows (64x100 floats = 25.6 KB) into LDS with fully
// coalesced float4 loads (4 KB per wave-instruction). 4 threads per row scan
// 25 floats each (bank layout verified: exactly 2 lanes/bank = free).
// Strict-> scan + lower-index tie-break = jnp.argmax semantics.
// ---------------------------------------------------------------------------
__global__ void argmax_kernel(const float* __restrict__ yS, const float* __restrict__ yT,
                              int* __restrict__ lbl, float* __restrict__ w,
                              int* __restrict__ cntPart, int n, int NB) {
    const int t = blockIdx.y;
    const float* __restrict__ y = t ? yT : yS;

    __shared__ float ly[RB * N_CLASS];    // 25.6 KB
    __shared__ int hist[N_CLASS];
    const int tid = threadIdx.x;
    if (tid < N_CLASS) hist[tid] = 0;

    const float4* __restrict__ src = (const float4*)(y + (size_t)blockIdx.x * (RB * N_CLASS));
    for (int i = tid; i < RB * N_CLASS / 4; i += 256)
        ((float4*)ly)[i] = src[i];
    __syncthreads();

    const int row = tid >> 2;         // 0..63
    const int q = tid & 3;            // quarter of the row
    const int base = row * N_CLASS + q * 25;

    float best = -3.4e38f;
    int bi = 0;
    #pragma unroll
    for (int k = 0; k < 25; ++k) {
        float v = ly[base + k];
        if (v > best) { best = v; bi = q * 25 + k; }
    }
    // reduce across the 4 adjacent lanes (q varies fastest)
    #pragma unroll
    for (int off = 1; off <= 2; off <<= 1) {
        float ov = __shfl_xor(best, off, 64);
        int   oi = __shfl_xor(bi, off, 64);
        if (ov > best || (ov == best && oi < bi)) { best = ov; bi = oi; }
    }
    if (q == 0) {
        const int grow = blockIdx.x * RB + row;
        lbl[(size_t)t * n + grow] = bi;
        w[(size_t)t * n + grow] = (best > THRESH) ? best : 0.0f;
        atomicAdd(&hist[bi], 1);
    }
    __syncthreads();
    if (tid < N_CLASS) cntPart[(t * N_CLASS + tid) * NB + blockIdx.x] = hist[tid];
}

// ---------------------------------------------------------------------------
// K2a: per-(tensor,class) exclusive scan over NB block-counts.
// 200 blocks x 256 threads, 8 elements/thread (NB = 2048).
// ---------------------------------------------------------------------------
__global__ void scan_kernel(const int* __restrict__ cntPart, int* __restrict__ relOff,
                            int* __restrict__ totals, int NB) {
    const int tc = blockIdx.x;
    const int* __restrict__ src = cntPart + (size_t)tc * NB;
    int* __restrict__ dst = relOff + (size_t)tc * NB;
    const int tid = threadIdx.x;
    const int EPT = NB / 256;     // 8

    int v[8];
    int s = 0;
    for (int k = 0; k < EPT; ++k) { v[k] = src[tid * EPT + k]; s += v[k]; }

    __shared__ int ls[256];
    ls[tid] = s;
    __syncthreads();
    for (int off = 1; off < 256; off <<= 1) {
        int x = (tid >= off) ? ls[tid - off] : 0;
        __syncthreads();
        ls[tid] += x;
        __syncthreads();
    }
    int run = (tid ? ls[tid - 1] : 0);
    for (int k = 0; k < EPT; ++k) { dst[tid * EPT + k] = run; run += v[k]; }
    if (tid == 255) totals[tc] = run;
}

// ---------------------------------------------------------------------------
// K2b: exclusive scan of 100 class totals per tensor -> classBase.
// 1 block x 256 threads (128 per tensor).
// ---------------------------------------------------------------------------
__global__ void base_kernel(const int* __restrict__ totals, int* __restrict__ classBase) {
    __shared__ int ls[2][128];
    const int t = threadIdx.x >> 7;
    const int c = threadIdx.x & 127;
    int v = (c < N_CLASS) ? totals[t * N_CLASS + c] : 0;
    ls[t][c] = v;
    __syncthreads();
    for (int off = 1; off < 128; off <<= 1) {
        int x = (c >= off) ? ls[t][c - off] : 0;
        __syncthreads();
        ls[t][c] += x;
        __syncthreads();
    }
    if (c < N_CLASS) classBase[t * N_CLASS + c] = ls[t][c] - v;   // exclusive
}

// ---------------------------------------------------------------------------
// K3: bucket rows into class-sorted order. grid (NB, 2) x 64 threads.
// ---------------------------------------------------------------------------
__global__ void bucket_kernel(const int* __restrict__ lbl, const float* __restrict__ w,
                              const int* __restrict__ relOff, const int* __restrict__ classBase,
                              int* __restrict__ sIdx, float* __restrict__ sW, int n, int NB) {
    const int t = blockIdx.y;
    const int b = blockIdx.x;
    __shared__ int cursor[N_CLASS];
    const int tid = threadIdx.x;
    for (int c = tid; c < N_CLASS; c += 64)
        cursor[c] = classBase[t * N_CLASS + c] + relOff[(size_t)(t * N_CLASS + c) * NB + b];
    __syncthreads();
    const int row = b * RB + tid;
    const int l = lbl[(size_t)t * n + row];
    const float wt = w[(size_t)t * n + row];
    const int pos = atomicAdd(&cursor[l], 1);
    sIdx[(size_t)t * n + pos] = row;
    sW[(size_t)t * n + pos] = wt;
}

// ---------------------------------------------------------------------------
// K4: gather-reduce. grid (100, NSLICE, 2) x 256 threads.
// One wave-instruction reads one full 1 KB row (64 lanes x float4).
// Pure register FMA accumulation -- no atomics, no LDS in the loop.
// ---------------------------------------------------------------------------
__global__ void __launch_bounds__(256, 4)
gather_kernel(const float* __restrict__ fS, const float* __restrict__ fT,
              const int* __restrict__ sIdx, const float* __restrict__ sW,
              const int* __restrict__ totals, const int* __restrict__ classBase,
              float* __restrict__ partial, int n) {
    const int c = blockIdx.x;
    const int s = blockIdx.y;
    const int t = blockIdx.z;
    const float* __restrict__ f = t ? fT : fS;
    const int* __restrict__ si = sIdx + (size_t)t * n;
    const float* __restrict__ sw = sW + (size_t)t * n;

    const int start = classBase[t * N_CLASS + c];
    const int cnt = totals[t * N_CLASS + c];
    const int per = (cnt + NSLICE - 1) / NSLICE;
    int lo = start + s * per;
    int hi = start + cnt;
    if (lo + per < hi) hi = lo + per;
    if (hi < lo) hi = lo;

    const int tid = threadIdx.x;
    const int lane = tid & 63;
    const int wv = tid >> 6;

    float4 acc = {0.f, 0.f, 0.f, 0.f};
    const int span = hi - lo;
    const int m = span / 32;          // full 32-row super-batches (8 per wave)

    for (int kk = 0; kk < m; ++kk) {
        const int i = lo + kk * 32 + wv * 8;
        int idx[8];
        float wt[8];
        #pragma unroll
        for (int j = 0; j < 8; ++j) { idx[j] = si[i + j]; wt[j] = sw[i + j]; }
        #pragma unroll
        for (int j = 0; j < 8; ++j) {
            const float4 v = *(const float4*)(f + (size_t)idx[j] * D + lane * 4);
            acc.x += wt[j] * v.x; acc.y += wt[j] * v.y;
            acc.z += wt[j] * v.z; acc.w += wt[j] * v.w;
        }
    }
    // tail rows, one row per wave-iteration
    for (int r = lo + m * 32 + wv; r < hi; r += 4) {
        const int idx = si[r];
        const float wt = sw[r];
        const float4 v = *(const float4*)(f + (size_t)idx * D + lane * 4);
        acc.x += wt * v.x; acc.y += wt * v.y; acc.z += wt * v.z; acc.w += wt * v.w;
    }

    __shared__ float4 red[4][64];
    red[wv][lane] = acc;
    __syncthreads();
    if (wv == 0) {
        float4 a0 = red[0][lane], a1 = red[1][lane], a2 = red[2][lane], a3 = red[3][lane];
        float4 r4;
        r4.x = a0.x + a1.x + a2.x + a3.x;
        r4.y = a0.y + a1.y + a2.y + a3.y;
        r4.z = a0.z + a1.z + a2.z + a3.z;
        r4.w = a0.w + a1.w + a2.w + a3.w;
        *(float4*)(partial + (size_t)((t * N_CLASS + c) * NSLICE + s) * D + lane * 4) = r4;
    }
}

// ---------------------------------------------------------------------------
// K5: finalize. 100 blocks x 256 threads (thread = column).
// ---------------------------------------------------------------------------
__global__ void finalize_kernel(const float* __restrict__ partial, const int* __restrict__ totals,
                                const float* __restrict__ cS, const float* __restrict__ cT,
                                float* __restrict__ out) {
    const int c = blockIdx.x;
    const int j = threadIdx.x;

    float sS = 0.f, sT = 0.f;
    #pragma unroll
    for (int s = 0; s < NSLICE; ++s) {
        sS += partial[(size_t)((0 * N_CLASS + c) * NSLICE + s) * D + j];
        sT += partial[(size_t)((1 * N_CLASS + c) * NSLICE + s) * D + j];
    }
    const float cntS = fmaxf((float)totals[c], 1.0f);
    const float cntT = fmaxf((float)totals[N_CLASS + c], 1.0f);
    const float a = KEEPF * cS[c * D + j] + DECAYF * sS / cntS;
    const float b = KEEPF * cT[c * D + j] + DECAYF * sT / cntT;
    const float d = a - b;
    float val = d * d;

    #pragma unroll
    for (int off = 32; off; off >>= 1) val += __shfl_xor(val, off, 64);
    __shared__ float red[4];
    if ((j & 63) == 0) red[j >> 6] = val;
    __syncthreads();
    if (j == 0)
        unsafeAtomicAdd(out, (red[0] + red[1] + red[2] + red[3]) * (1.0f / (N_CLASS * D)));
}

extern "C" void kernel_launch(void* const* d_in, const int* in_sizes, int n_in,
                              void* d_out, int out_size, void* d_ws, size_t ws_size,
                              hipStream_t stream) {
    const float* s_feature = (const float*)d_in[0];
    const float* t_feature = (const float*)d_in[1];
    const float* y_s = (const float*)d_in[2];
    const float* y_t = (const float*)d_in[3];
    const float* s_centroid = (const float*)d_in[4];
    const float* t_centroid = (const float*)d_in[5];
    float* out = (float*)d_out;

    const int n = in_sizes[0] / D;   // 131072
    const int NB = n / RB;           // 2048

    // workspace layout (all segment sizes are multiples of 16 B)
    int* lbl = (int*)d_ws;                              // 2n
    float* w = (float*)(lbl + 2 * n);                   // 2n
    int* cntPart = (int*)(w + 2 * n);                   // 2*100*NB
    int* relOff = cntPart + 2 * N_CLASS * NB;           // 2*100*NB
    int* totals = relOff + 2 * N_CLASS * NB;            // 256 (200 used)
    int* classBase = totals + 256;                      // 256 (200 used)
    int* sIdx = classBase + 256;                        // 2n
    float* sW = (float*)(sIdx + 2 * n);                 // 2n
    float* partial = sW + 2 * n;                        // 2*100*NSLICE*256

    hipMemsetAsync(out, 0, sizeof(float), stream);

    argmax_kernel<<<dim3(NB, 2), 256, 0, stream>>>(y_s, y_t, lbl, w, cntPart, n, NB);
    scan_kernel<<<2 * N_CLASS, 256, 0, stream>>>(cntPart, relOff, totals, NB);
    base_kernel<<<1, 256, 0, stream>>>(totals, classBase);
    bucket_kernel<<<dim3(NB, 2), 64, 0, stream>>>(lbl, w, relOff, classBase, sIdx, sW, n, NB);
    gather_kernel<<<dim3(N_CLASS, NSLICE, 2), 256, 0, stream>>>(s_feature, t_feature, sIdx, sW,
                                                                totals, classBase, partial, n);
    finalize_kernel<<<N_CLASS, 256, 0, stream>>>(partial, totals, s_centroid, t_centroid, out);
}

// Round 5
// 370.766 us; speedup vs baseline: 3.1418x; 1.0078x over previous
//
#include <hip/hip_runtime.h>

#define N_CLASS 100
#define D 256
#define DECAYF 0.3f
#define KEEPF 0.7f
#define THRESH 0.9f
#define RB 64          // rows per argmax block (count granularity)
#define BB 256         // rows per bucket block (4 argmax blocks)
#define NSLICE 8       // gather slices per class

// ---------------------------------------------------------------------------
// K1: argmax. Stage 64 rows (64x100 floats = 25.6 KB) into LDS with fully
// coalesced float4 loads. 4 threads/row scan 25 floats each (2 lanes/bank =
// free). Strict-> scan + lower-index tie-break = jnp.argmax semantics.
// ---------------------------------------------------------------------------
__global__ void argmax_kernel(const float* __restrict__ yS, const float* __restrict__ yT,
                              int* __restrict__ lbl, float* __restrict__ w,
                              int* __restrict__ cntPart, int n, int NB) {
    const int t = blockIdx.y;
    const float* __restrict__ y = t ? yT : yS;

    __shared__ float ly[RB * N_CLASS];    // 25.6 KB
    __shared__ int hist[N_CLASS];
    const int tid = threadIdx.x;
    if (tid < N_CLASS) hist[tid] = 0;

    const float4* __restrict__ src = (const float4*)(y + (size_t)blockIdx.x * (RB * N_CLASS));
    for (int i = tid; i < RB * N_CLASS / 4; i += 256)
        ((float4*)ly)[i] = src[i];
    __syncthreads();

    const int row = tid >> 2;
    const int q = tid & 3;
    const int base = row * N_CLASS + q * 25;

    float best = -3.4e38f;
    int bi = 0;
    #pragma unroll
    for (int k = 0; k < 25; ++k) {
        float v = ly[base + k];
        if (v > best) { best = v; bi = q * 25 + k; }
    }
    #pragma unroll
    for (int off = 1; off <= 2; off <<= 1) {
        float ov = __shfl_xor(best, off, 64);
        int   oi = __shfl_xor(bi, off, 64);
        if (ov > best || (ov == best && oi < bi)) { best = ov; bi = oi; }
    }
    if (q == 0) {
        const int grow = blockIdx.x * RB + row;
        lbl[(size_t)t * n + grow] = bi;
        w[(size_t)t * n + grow] = (best > THRESH) ? best : 0.0f;
        atomicAdd(&hist[bi], 1);
    }
    __syncthreads();
    if (tid < N_CLASS) cntPart[(t * N_CLASS + tid) * NB + blockIdx.x] = hist[tid];
}

// ---------------------------------------------------------------------------
// K2a: per-(tensor,class) exclusive scan over NB block-counts.
// ---------------------------------------------------------------------------
__global__ void scan_kernel(const int* __restrict__ cntPart, int* __restrict__ relOff,
                            int* __restrict__ totals, int NB) {
    const int tc = blockIdx.x;
    const int* __restrict__ src = cntPart + (size_t)tc * NB;
    int* __restrict__ dst = relOff + (size_t)tc * NB;
    const int tid = threadIdx.x;
    const int EPT = NB / 256;     // 8

    int v[8];
    int s = 0;
    for (int k = 0; k < EPT; ++k) { v[k] = src[tid * EPT + k]; s += v[k]; }

    __shared__ int ls[256];
    ls[tid] = s;
    __syncthreads();
    for (int off = 1; off < 256; off <<= 1) {
        int x = (tid >= off) ? ls[tid - off] : 0;
        __syncthreads();
        ls[tid] += x;
        __syncthreads();
    }
    int run = (tid ? ls[tid - 1] : 0);
    for (int k = 0; k < EPT; ++k) { dst[tid * EPT + k] = run; run += v[k]; }
    if (tid == 255) totals[tc] = run;
}

// ---------------------------------------------------------------------------
// K2b: exclusive scan of 100 class totals per tensor -> classBase.
// ---------------------------------------------------------------------------
__global__ void base_kernel(const int* __restrict__ totals, int* __restrict__ classBase) {
    __shared__ int ls[2][128];
    const int t = threadIdx.x >> 7;
    const int c = threadIdx.x & 127;
    int v = (c < N_CLASS) ? totals[t * N_CLASS + c] : 0;
    ls[t][c] = v;
    __syncthreads();
    for (int off = 1; off < 128; off <<= 1) {
        int x = (c >= off) ? ls[t][c - off] : 0;
        __syncthreads();
        ls[t][c] += x;
        __syncthreads();
    }
    if (c < N_CLASS) classBase[t * N_CLASS + c] = ls[t][c] - v;   // exclusive
}

// ---------------------------------------------------------------------------
// K3: bucket rows into class-sorted order, packed (row, weight) int2 stores.
// 256 rows/block; cursor base = prefix at this superblock's first sub-block.
// Intra-bucket permutation is fine: gather sums the whole bucket.
// ---------------------------------------------------------------------------
__global__ void bucket_kernel(const int* __restrict__ lbl, const float* __restrict__ w,
                              const int* __restrict__ relOff, const int* __restrict__ classBase,
                              int2* __restrict__ sPair, int n, int NB) {
    const int t = blockIdx.y;
    const int b = blockIdx.x;              // superblock of 4 argmax blocks
    __shared__ int cursor[N_CLASS];
    const int tid = threadIdx.x;
    if (tid < N_CLASS)
        cursor[tid] = classBase[t * N_CLASS + tid] +
                      relOff[(size_t)(t * N_CLASS + tid) * NB + 4 * b];
    __syncthreads();
    const int row = b * BB + tid;
    const int l = lbl[(size_t)t * n + row];
    const float wt = w[(size_t)t * n + row];
    const int pos = atomicAdd(&cursor[l], 1);
    sPair[(size_t)t * n + pos] = make_int2(row, __float_as_int(wt));
}

// ---------------------------------------------------------------------------
// K4: gather-reduce. grid (100, NSLICE, 2) x 256 threads.
// Software-pipelined: batch of 8 packed pairs prefetched while the current
// batch's 8 independent 1 KB row loads are in flight (v[8] array forces MLP).
// ---------------------------------------------------------------------------
__global__ void __launch_bounds__(256, 4)
gather_kernel(const float* __restrict__ fS, const float* __restrict__ fT,
              const int2* __restrict__ sPair,
              const int* __restrict__ totals, const int* __restrict__ classBase,
              float* __restrict__ partial, int n) {
    const int c = blockIdx.x;
    const int s = blockIdx.y;
    const int t = blockIdx.z;
    const float* __restrict__ f = t ? fT : fS;
    const int2* __restrict__ sp = sPair + (size_t)t * n;

    const int start = classBase[t * N_CLASS + c];
    const int cnt = totals[t * N_CLASS + c];
    const int per = (cnt + NSLICE - 1) / NSLICE;
    int lo = start + s * per;
    int hi = start + cnt;
    if (lo + per < hi) hi = lo + per;
    if (hi < lo) hi = lo;

    const int tid = threadIdx.x;
    const int lane = tid & 63;
    const int wv = tid >> 6;

    float4 acc = {0.f, 0.f, 0.f, 0.f};
    const int span = hi - lo;
    const int m = span / 32;          // full 32-row super-batches (8/wave)

    int2 p[8];
    if (m > 0) {
        const int i0 = lo + wv * 8;
        #pragma unroll
        for (int j = 0; j < 8; ++j) p[j] = sp[i0 + j];
    }
    for (int kk = 0; kk < m; ++kk) {
        // phase 1: issue all 8 independent row loads
        float4 v[8];
        #pragma unroll
        for (int j = 0; j < 8; ++j)
            v[j] = *(const float4*)(f + (size_t)p[j].x * D + lane * 4);
        // phase 2: prefetch next batch's pairs (independent of v)
        int2 np[8];
        if (kk + 1 < m) {
            const int i1 = lo + (kk + 1) * 32 + wv * 8;
            #pragma unroll
            for (int j = 0; j < 8; ++j) np[j] = sp[i1 + j];
        }
        // phase 3: accumulate
        #pragma unroll
        for (int j = 0; j < 8; ++j) {
            const float wt = __int_as_float(p[j].y);
            acc.x += wt * v[j].x; acc.y += wt * v[j].y;
            acc.z += wt * v[j].z; acc.w += wt * v[j].w;
        }
        #pragma unroll
        for (int j = 0; j < 8; ++j) p[j] = np[j];
    }
    // tail rows
    for (int r = lo + m * 32 + wv; r < hi; r += 4) {
        const int2 pr = sp[r];
        const float wt = __int_as_float(pr.y);
        const float4 v = *(const float4*)(f + (size_t)pr.x * D + lane * 4);
        acc.x += wt * v.x; acc.y += wt * v.y; acc.z += wt * v.z; acc.w += wt * v.w;
    }

    __shared__ float4 red[4][64];
    red[wv][lane] = acc;
    __syncthreads();
    if (wv == 0) {
        float4 a0 = red[0][lane], a1 = red[1][lane], a2 = red[2][lane], a3 = red[3][lane];
        float4 r4;
        r4.x = a0.x + a1.x + a2.x + a3.x;
        r4.y = a0.y + a1.y + a2.y + a3.y;
        r4.z = a0.z + a1.z + a2.z + a3.z;
        r4.w = a0.w + a1.w + a2.w + a3.w;
        *(float4*)(partial + (size_t)((t * N_CLASS + c) * NSLICE + s) * D + lane * 4) = r4;
    }
}

// ---------------------------------------------------------------------------
// K5: finalize. 100 blocks x 256 threads (thread = column).
// ---------------------------------------------------------------------------
__global__ void finalize_kernel(const float* __restrict__ partial, const int* __restrict__ totals,
                                const float* __restrict__ cS, const float* __restrict__ cT,
                                float* __restrict__ out) {
    const int c = blockIdx.x;
    const int j = threadIdx.x;

    float sS = 0.f, sT = 0.f;
    #pragma unroll
    for (int s = 0; s < NSLICE; ++s) {
        sS += partial[(size_t)((0 * N_CLASS + c) * NSLICE + s) * D + j];
        sT += partial[(size_t)((1 * N_CLASS + c) * NSLICE + s) * D + j];
    }
    const float cntS = fmaxf((float)totals[c], 1.0f);
    const float cntT = fmaxf((float)totals[N_CLASS + c], 1.0f);
    const float a = KEEPF * cS[c * D + j] + DECAYF * sS / cntS;
    const float b = KEEPF * cT[c * D + j] + DECAYF * sT / cntT;
    const float d = a - b;
    float val = d * d;

    #pragma unroll
    for (int off = 32; off; off >>= 1) val += __shfl_xor(val, off, 64);
    __shared__ float red[4];
    if ((j & 63) == 0) red[j >> 6] = val;
    __syncthreads();
    if (j == 0)
        unsafeAtomicAdd(out, (red[0] + red[1] + red[2] + red[3]) * (1.0f / (N_CLASS * D)));
}

extern "C" void kernel_launch(void* const* d_in, const int* in_sizes, int n_in,
                              void* d_out, int out_size, void* d_ws, size_t ws_size,
                              hipStream_t stream) {
    const float* s_feature = (const float*)d_in[0];
    const float* t_feature = (const float*)d_in[1];
    const float* y_s = (const float*)d_in[2];
    const float* y_t = (const float*)d_in[3];
    const float* s_centroid = (const float*)d_in[4];
    const float* t_centroid = (const float*)d_in[5];
    float* out = (float*)d_out;

    const int n = in_sizes[0] / D;   // 131072
    const int NB = n / RB;           // 2048

    // workspace layout (all segment sizes multiples of 16 B)
    int* lbl = (int*)d_ws;                              // 2n
    float* w = (float*)(lbl + 2 * n);                   // 2n
    int* cntPart = (int*)(w + 2 * n);                   // 2*100*NB
    int* relOff = cntPart + 2 * N_CLASS * NB;           // 2*100*NB
    int* totals = relOff + 2 * N_CLASS * NB;            // 256 (200 used)
    int* classBase = totals + 256;                      // 256 (200 used)
    int2* sPair = (int2*)(classBase + 256);             // 2n int2
    float* partial = (float*)(sPair + 2 * n);           // 2*100*NSLICE*256

    hipMemsetAsync(out, 0, sizeof(float), stream);

    argmax_kernel<<<dim3(NB, 2), 256, 0, stream>>>(y_s, y_t, lbl, w, cntPart, n, NB);
    scan_kernel<<<2 * N_CLASS, 256, 0, stream>>>(cntPart, relOff, totals, NB);
    base_kernel<<<1, 256, 0, stream>>>(totals, classBase);
    bucket_kernel<<<dim3(n / BB, 2), BB, 0, stream>>>(lbl, w, relOff, classBase, sPair, n, NB);
    gather_kernel<<<dim3(N_CLASS, NSLICE, 2), 256, 0, stream>>>(s_feature, t_feature, sPair,
                                                                totals, classBase, partial, n);
    finalize_kernel<<<N_CLASS, 256, 0, stream>>>(partial, totals, s_centroid, t_centroid, out);
}